// Round 9
// baseline (220.259 us; speedup 1.0000x reference)
//
#include <hip/hip_runtime.h>
#include <math.h>

// DVGO volume-rendering forward, round 18.
// Model (fits ALL experiments r9-r17): dvgo is bound by aggregate
// instruction issue-work: ~250-300 instr/live-chunk x 128 waves/CU / 4
// SIMDs ~= 48 us — the stubborn number. Bytes(r12)/vmem-count(r10)/
// occupancy(r10)/latency(r15)/scan(r17) theories all falsified.
// r18 = r17 skeleton (4 waves/ray, round-robin chunks, LDS chunk-product
// prefix, interleaved stores) with the hot path slimmed ~35-40%:
//  1. packed consume: cvt_pk_f32_fp8 (2 ch/instr) + float2 accumulators
//     (v_pk_fma_f32): 64->32 instr off, 128->64 on.
//  2. geometry computed ONCE per chunk (r17 ran it twice: prefetch addr +
//     consume weights); incremental fx = fma(s, gsx, fxb) replaces the
//     t/px/fx chain (3 fma total).
//  3. wave-uniform fast path when ballot(interior)==~0: no clamps, no
//     valid masks, offset-chained corner addresses. Partial waves use the
//     proven clamped path (loads always in-bounds).
// Predicted: dvgo ~49 -> 33-37 us, total 218 -> ~202-206; WRITE ~99MB,
// FETCH ~55MB unchanged (instruction diet, not traffic); VALUBusy -> ~32%.
// If flat: instruction model dead -> next round ablation-measures floor.

namespace {
constexpr int   kR   = 8192;
constexpr int   kS   = 558;
constexpr int   kNC  = (kS + 63) / 64;            // 9 chunks
constexpr int   kG   = 160;
constexpr int   kG3  = kG * kG * kG;
constexpr float kNear = 0.05f;
constexpr float kFar  = 6.0f;
constexpr float kStepWorld = 0.5f * (2.0f / 160.0f);  // STEPSIZE * VOXEL_SIZE
constexpr float kActShift = -13.815509557963774f;     // log(1/(1-1e-6)-1)
constexpr float kLog2e = 1.4426950408889634f;
// brick layout: 2x2x4 voxels, 16 records x 4B = 64B = one cache line
constexpr int   kBX = 80, kBY = 80, kBZ = 40;
constexpr int   kNB = kBX * kBY * kBZ;            // 256000 bricks
constexpr int   kGridWords = kNB * 16;            // 16.4 MB per grid
constexpr int   kXS = kBY * kBZ * 16;             // x-brick stride in words
constexpr int   kYS = kBZ * 16;                   // y-brick stride in words
}

typedef unsigned int nuint4 __attribute__((ext_vector_type(4)));
typedef float        nfloat2 __attribute__((ext_vector_type(2)));
typedef float        nfloat4 __attribute__((ext_vector_type(4)));

__device__ __forceinline__ float fexp(float x) {   // e^x
  return __builtin_amdgcn_exp2f(x * kLog2e);
}
__device__ __forceinline__ float sigmoidf_(float x) {
  return __builtin_amdgcn_rcpf(1.0f + fexp(-x));
}

// ---- repack: planar 7-channel f32 -> two bricked fp8 grids (r12, proven) ----
__global__ __launch_bounds__(256) void repack_grids(
    const float* __restrict__ density,
    const float* __restrict__ off_c,
    const float* __restrict__ emo_c,
    unsigned* __restrict__ gridA,    // [kNB*16] dens|off0|off1|off2
    unsigned* __restrict__ gridB)    // [kNB*16] emo0|emo1|emo2|0
{
  const int t   = blockIdx.x * blockDim.x + threadIdx.x;
  const int bid = t >> 2;
  const int q   = t & 3;
  if (bid >= kNB) return;
  const int bz = bid % kBZ;
  const int u  = bid / kBZ;
  const int by = u % kBY;
  const int bx = u / kBY;
  const int x  = bx * 2 + (q >> 1);
  const int y  = by * 2 + (q & 1);
  const int z0 = bz * 4;
  const int vbase = (x * kG + y) * kG + z0;

  const nfloat4 d  = __builtin_nontemporal_load((const nfloat4*)(density + vbase));
  const nfloat4 f0 = __builtin_nontemporal_load((const nfloat4*)(off_c + vbase));
  const nfloat4 f1 = __builtin_nontemporal_load((const nfloat4*)(off_c + vbase + kG3));
  const nfloat4 f2 = __builtin_nontemporal_load((const nfloat4*)(off_c + vbase + 2 * kG3));
  const nfloat4 e0 = __builtin_nontemporal_load((const nfloat4*)(emo_c + vbase));
  const nfloat4 e1 = __builtin_nontemporal_load((const nfloat4*)(emo_c + vbase + kG3));
  const nfloat4 e2 = __builtin_nontemporal_load((const nfloat4*)(emo_c + vbase + 2 * kG3));

  nuint4 va, vb;
  #pragma unroll
  for (int lz = 0; lz < 4; ++lz) {
    int qa = __builtin_amdgcn_cvt_pk_fp8_f32(d[lz],  f0[lz], 0,  false);
    qa     = __builtin_amdgcn_cvt_pk_fp8_f32(f1[lz], f2[lz], qa, true);
    int qb = __builtin_amdgcn_cvt_pk_fp8_f32(e0[lz], e1[lz], 0,  false);
    qb     = __builtin_amdgcn_cvt_pk_fp8_f32(e2[lz], 0.0f,   qb, true);
    va[lz] = (unsigned)qa;
    vb[lz] = (unsigned)qb;
  }
  const size_t woff = (size_t)bid * 16 + q * 4;
  __builtin_nontemporal_store(va, (nuint4*)(gridA + woff));
  __builtin_nontemporal_store(vb, (nuint4*)(gridB + woff));
}

// ---- main: one block (4 waves) per ray; round-robin chunk ownership ----
__global__ __launch_bounds__(256) void dvgo_fwd(
    const float* __restrict__ rays_o,
    const float* __restrict__ rays_d,
    const float* __restrict__ jitter,
    const int*   __restrict__ em_modes,
    const unsigned* __restrict__ gridA,
    const unsigned* __restrict__ gridB,
    float* __restrict__ out)
{
  const int ray  = blockIdx.x;
  const int wv   = (threadIdx.x >> 6) & 3;
  const int lane = threadIdx.x & 63;

  __shared__ float s_prod[kNC];
  __shared__ float s_acc[4][3];

  const float ox = rays_o[ray * 3 + 0];
  const float oy = rays_o[ray * 3 + 1];
  const float oz = rays_o[ray * 3 + 2];
  const float dx = rays_d[ray * 3 + 0];
  const float dy = rays_d[ray * 3 + 1];
  const float dz = rays_d[ray * 3 + 2];
  const float jit = jitter[ray];
  const bool  on  = (em_modes[ray] == 1);

  const float vx = (dx == 0.0f) ? 1e-6f : dx;
  const float vy = (dy == 0.0f) ? 1e-6f : dy;
  const float vz = (dz == 0.0f) ? 1e-6f : dz;
  const float ivx = __builtin_amdgcn_rcpf(vx);
  const float ivy = __builtin_amdgcn_rcpf(vy);
  const float ivz = __builtin_amdgcn_rcpf(vz);
  const float rax = ( 1.0f - ox) * ivx, rbx = (-1.0f - ox) * ivx;
  const float ray_a = ( 1.0f - oy) * ivy, rby = (-1.0f - oy) * ivy;
  const float raz = ( 1.0f - oz) * ivz, rbz = (-1.0f - oz) * ivz;
  float tmin = fmaxf(fmaxf(fminf(rax, rbx), fminf(ray_a, rby)), fminf(raz, rbz));
  float tmax = fminf(fminf(fmaxf(rax, rbx), fmaxf(ray_a, rby)), fmaxf(raz, rbz));
  tmin = fminf(fmaxf(tmin, kNear), kFar);
  tmax = fminf(fmaxf(tmax, kNear), kFar);
  const bool  ray_out = (tmax <= tmin);
  const float stepc = kStepWorld *
      __builtin_amdgcn_rsqf(dx * dx + dy * dy + dz * dz);

  // incremental grid-space geometry: fx(s) = fxb + s*gsx  (1 fma per axis)
  const float sc   = 0.5f * (float)(kG - 1);
  const float t0   = tmin + stepc * jit;
  const float fxb  = (fmaf(dx, t0, ox) + 1.0f) * sc;
  const float fyb  = (fmaf(dy, t0, oy) + 1.0f) * sc;
  const float fzb  = (fmaf(dz, t0, oz) + 1.0f) * sc;
  const float gsx  = dx * stepc * sc;
  const float gsy  = dy * stepc * sc;
  const float gsz  = dz * stepc * sc;

  float* out_ainv = out;                     // [R, S+1]
  float* out_w    = out + kR * (kS + 1);     // [R, S]
  float* out_last = out_w + kR * kS;         // [R, 1]
  float* out_rgb  = out_last + kR;           // [R, S, 3]
  float* out_rm   = out_rgb + kR * kS * 3;   // [R, 3]

  const int base_ainv = ray * (kS + 1);
  const int base_w    = ray * kS;

  if (threadIdx.x == 0)
    __builtin_nontemporal_store(1.0f, out_ainv + base_ainv);

  const float c_base = on ? 1.0f : 0.5f;  // sigma(0) (+sigma(0) if on)

  // --- prepare chunk c: geometry ONCE, weights + issue gathers ---
  // live: any lane reaches; masked/w8 per-lane; loads always in-bounds.
  auto prep = [&](int c, float w8[8], unsigned ua[8], unsigned ub[8],
                  bool& live, bool& masked) {
    const int   s  = c * 64 + lane;
    const bool  ac = (s < kS);
    const float sf = (float)s;
    const float fx = fmaf(sf, gsx, fxb);
    const float fy = fmaf(sf, gsy, fyb);
    const float fz = fmaf(sf, gsz, fzb);
    const int ix = (int)floorf(fx);
    const int iy = (int)floorf(fy);
    const int iz = (int)floorf(fz);
    const bool inb = (fx >= 0.0f) & (fx <= (float)(kG - 1)) &
                     (fy >= 0.0f) & (fy <= (float)(kG - 1)) &
                     (fz >= 0.0f) & (fz <= (float)(kG - 1));
    masked = ray_out || !inb;
    const bool reach = ac &&
        ((unsigned)(ix + 1) < (unsigned)(kG + 1)) &&
        ((unsigned)(iy + 1) < (unsigned)(kG + 1)) &&
        ((unsigned)(iz + 1) < (unsigned)(kG + 1));
    const unsigned long long bal_reach = __ballot(reach);
    live = (bal_reach != 0ull);
    if (!live) return;

    const float wx = fx - (float)ix;
    const float wy = fy - (float)iy;
    const float wz = fz - (float)iz;
    const float x0 = 1.0f - wx, y0 = 1.0f - wy, z0 = 1.0f - wz;
    const float wxy00 = x0 * y0, wxy01 = x0 * wy;
    const float wxy10 = wx * y0, wxy11 = wx * wy;

    const bool interior = ac &&
        ((unsigned)ix < (unsigned)(kG - 1)) &&
        ((unsigned)iy < (unsigned)(kG - 1)) &&
        ((unsigned)iz < (unsigned)(kG - 1));
    const bool fastp = (__ballot(interior) == ~0ull);  // wave-uniform

    int wi[8];
    if (fastp) {
      // all 64 lanes strictly interior: no clamps, no valid masks
      w8[0] = wxy00 * z0; w8[1] = wxy00 * wz;
      w8[2] = wxy01 * z0; w8[3] = wxy01 * wz;
      w8[4] = wxy10 * z0; w8[5] = wxy10 * wz;
      w8[6] = wxy11 * z0; w8[7] = wxy11 * wz;
      const int ax0 = (ix >> 1) * kXS + (ix & 1) * 8;
      const int ay0 = (iy >> 1) * kYS + (iy & 1) * 4;
      const int az0 = (iz >> 2) * 16 + (iz & 3);
      const int xof = (ix & 1) ? (kXS - 8) : 8;
      const int yof = (iy & 1) ? (kYS - 4) : 4;
      const int zof = ((iz & 3) == 3) ? 13 : 1;
      wi[0] = ax0 + ay0 + az0;
      wi[1] = wi[0] + zof;
      wi[2] = wi[0] + yof;
      wi[3] = wi[2] + zof;
      wi[4] = wi[0] + xof;
      wi[5] = wi[4] + zof;
      wi[6] = wi[4] + yof;
      wi[7] = wi[6] + zof;
    } else {
      // partial wave: clamped addresses + per-corner valid masks (r17 path)
      const bool vx0 = ((unsigned)ix       < (unsigned)kG);
      const bool vx1 = ((unsigned)(ix + 1) < (unsigned)kG);
      const bool vy0 = ((unsigned)iy       < (unsigned)kG);
      const bool vy1 = ((unsigned)(iy + 1) < (unsigned)kG);
      const bool vz0 = ((unsigned)iz       < (unsigned)kG);
      const bool vz1 = ((unsigned)(iz + 1) < (unsigned)kG);
      w8[0] = (vx0 & vy0 & vz0) ? wxy00 * z0 : 0.0f;
      w8[1] = (vx0 & vy0 & vz1) ? wxy00 * wz : 0.0f;
      w8[2] = (vx0 & vy1 & vz0) ? wxy01 * z0 : 0.0f;
      w8[3] = (vx0 & vy1 & vz1) ? wxy01 * wz : 0.0f;
      w8[4] = (vx1 & vy0 & vz0) ? wxy10 * z0 : 0.0f;
      w8[5] = (vx1 & vy0 & vz1) ? wxy10 * wz : 0.0f;
      w8[6] = (vx1 & vy1 & vz0) ? wxy11 * z0 : 0.0f;
      w8[7] = (vx1 & vy1 & vz1) ? wxy11 * wz : 0.0f;
      const int gx0 = min(max(ix, 0), kG - 1), gx1 = min(max(ix + 1, 0), kG - 1);
      const int gy0 = min(max(iy, 0), kG - 1), gy1 = min(max(iy + 1, 0), kG - 1);
      const int gz0 = min(max(iz, 0), kG - 1), gz1 = min(max(iz + 1, 0), kG - 1);
      const int X0 = (gx0 >> 1) * kXS + (gx0 & 1) * 8;
      const int X1 = (gx1 >> 1) * kXS + (gx1 & 1) * 8;
      const int Y0 = (gy0 >> 1) * kYS + (gy0 & 1) * 4;
      const int Y1 = (gy1 >> 1) * kYS + (gy1 & 1) * 4;
      const int Z0 = (gz0 >> 2) * 16 + (gz0 & 3);
      const int Z1 = (gz1 >> 2) * 16 + (gz1 & 3);
      wi[0] = X0 + Y0 + Z0; wi[1] = X0 + Y0 + Z1;
      wi[2] = X0 + Y1 + Z0; wi[3] = X0 + Y1 + Z1;
      wi[4] = X1 + Y0 + Z0; wi[5] = X1 + Y0 + Z1;
      wi[6] = X1 + Y1 + Z0; wi[7] = X1 + Y1 + Z1;
    }

    #pragma unroll
    for (int q = 0; q < 8; ++q) ua[q] = gridA[wi[q]];
    if (on) {
      #pragma unroll
      for (int q = 0; q < 8; ++q) ub[q] = gridB[wi[q]];
    }
  };

  float incl_a[3], excl_a[3], rr_a[3], gg_a[3], bb_a[3];

  // prologue: prepare first owned chunk (c = wv, always < kNC)
  float    cw8[8];
  unsigned cua[8], cub[8];
  bool cur_live = false, cur_masked = true;
  prep(wv, cw8, cua, cub, cur_live, cur_masked);

  // ---- phase A: per-owned-chunk p-scan + rgb (stores scan-independent) ----
  #pragma unroll
  for (int k = 0; k < 3; ++k) {
    const int c = wv + 4 * k;
    if (c < kNC) {
      const int s = c * 64 + lane;

      // prepare next owned chunk (loads overlap current consume below)
      float    nw8[8];
      unsigned nua[8], nub[8];
      bool nxt_live = false, nxt_masked = true;
      if (c + 4 < kNC)
        prep(c + 4, nw8, nua, nub, nxt_live, nxt_masked);

      float incl = 1.0f, excl = 1.0f;
      float rr = c_base, gg = c_base, bb = c_base;

      if (cur_live) {
        // packed consume: 2 channels per cvt, float2 fma accumulators
        nfloat2 a0 = {0.0f, 0.0f};   // (dens, off0)
        nfloat2 a1 = {0.0f, 0.0f};   // (off1, off2)
        nfloat2 b0 = {0.0f, 0.0f};   // (emo0, emo1)
        nfloat2 b1 = {0.0f, 0.0f};   // (emo2, pad)
        #pragma unroll
        for (int q = 0; q < 8; ++q) {
          nfloat2 w2; w2.x = cw8[q]; w2.y = cw8[q];
          a0 += w2 * __builtin_amdgcn_cvt_pk_f32_fp8((int)cua[q], false);
          a1 += w2 * __builtin_amdgcn_cvt_pk_f32_fp8((int)cua[q], true);
        }
        if (on) {
          #pragma unroll
          for (int q = 0; q < 8; ++q) {
            nfloat2 w2; w2.x = cw8[q]; w2.y = cw8[q];
            b0 += w2 * __builtin_amdgcn_cvt_pk_f32_fp8((int)cub[q], false);
            b1 += w2 * __builtin_amdgcn_cvt_pk_f32_fp8((int)cub[q], true);
          }
        }

        // p = (1+e^x)^-0.5 == exp(-softplus(x)*0.5); masked/inactive -> 1
        float p = 1.0f;
        if ((s < kS) && !cur_masked) {
          const float expx = fexp(a0.x + kActShift);
          p = fmaxf(__builtin_amdgcn_rsqf(1.0f + expx), 1e-10f);
        }

        // chunk-local inclusive product scan (proven construct)
        incl = p;
        #pragma unroll
        for (int o = 1; o < 64; o <<= 1) {
          const float n = __shfl_up(incl, o, 64);
          if (lane >= o) incl *= n;
        }
        excl = __shfl_up(incl, 1, 64);
        if (lane == 0) excl = 1.0f;

        rr = sigmoidf_(a0.y);
        gg = sigmoidf_(a1.x);
        bb = sigmoidf_(a1.y);
        if (on) {
          rr += sigmoidf_(b0.x);
          gg += sigmoidf_(b0.y);
          bb += sigmoidf_(b1.x);
        }
      }

      if (s < kS) {  // rgb has no scan dependency -> store now (coalesced)
        const int rb = (base_w + s) * 3;
        nfloat2 rg;
        rg.x = rr; rg.y = gg;
        __builtin_nontemporal_store(rg, (nfloat2*)(out_rgb + rb));
        __builtin_nontemporal_store(bb, out_rgb + rb + 2);
      }

      incl_a[k] = incl; excl_a[k] = excl;
      rr_a[k] = rr; gg_a[k] = gg; bb_a[k] = bb;

      const float prod = __shfl(incl, 63, 64);
      if (lane == 0) s_prod[c] = prod;

      cur_live = nxt_live;
      cur_masked = nxt_masked;
      #pragma unroll
      for (int q = 0; q < 8; ++q) { cw8[q] = nw8[q]; cua[q] = nua[q]; }
      if (on) {
        #pragma unroll
        for (int q = 0; q < 8; ++q) cub[q] = nub[q];
      }
    }
  }

  __syncthreads();

  float sp[kNC];
  #pragma unroll
  for (int i = 0; i < kNC; ++i) sp[i] = s_prod[i];

  // ---- phase B: chunk prefixes (uniform multiplies) + ainv/w/acc emit ----
  float accr = 0.0f, accg = 0.0f, accb = 0.0f;
  #pragma unroll
  for (int k = 0; k < 3; ++k) {
    const int c = wv + 4 * k;
    if (c < kNC) {
      float carry = 1.0f;
      #pragma unroll
      for (int i = 0; i < kNC; ++i) carry *= (i < c) ? sp[i] : 1.0f;
      const int s = c * 64 + lane;
      const float anext = carry * incl_a[k];
      const float aprev = carry * excl_a[k];
      const float wgt   = aprev - anext;   // alpha * ainv_prev
      if (s < kS) {
        __builtin_nontemporal_store(anext, out_ainv + base_ainv + s + 1);
        __builtin_nontemporal_store(wgt, out_w + base_w + s);
        accr = fmaf(wgt, rr_a[k], accr);
        accg = fmaf(wgt, gg_a[k], accg);
        accb = fmaf(wgt, bb_a[k], accb);
      }
    }
  }

  #pragma unroll
  for (int o = 32; o > 0; o >>= 1) {
    accr += __shfl_xor(accr, o, 64);
    accg += __shfl_xor(accg, o, 64);
    accb += __shfl_xor(accb, o, 64);
  }
  if (lane == 0) {
    s_acc[wv][0] = accr;
    s_acc[wv][1] = accg;
    s_acc[wv][2] = accb;
  }
  __syncthreads();

  if (threadIdx.x == 0) {
    out_rm[ray * 3 + 0] = s_acc[0][0] + s_acc[1][0] + s_acc[2][0] + s_acc[3][0];
    out_rm[ray * 3 + 1] = s_acc[0][1] + s_acc[1][1] + s_acc[2][1] + s_acc[3][1];
    out_rm[ray * 3 + 2] = s_acc[0][2] + s_acc[1][2] + s_acc[2][2] + s_acc[3][2];
    float tot = 1.0f;
    #pragma unroll
    for (int i = 0; i < kNC; ++i) tot *= sp[i];
    out_last[ray] = tot;
  }
}

extern "C" void kernel_launch(void* const* d_in, const int* in_sizes, int n_in,
                              void* d_out, int out_size, void* d_ws, size_t ws_size,
                              hipStream_t stream) {
  const float* rays_o  = (const float*)d_in[0];
  const float* rays_d  = (const float*)d_in[1];
  const float* jitter  = (const float*)d_in[2];
  const int*   em      = (const int*)d_in[3];
  const float* density = (const float*)d_in[4];
  const float* off_c   = (const float*)d_in[5];
  const float* emo_c   = (const float*)d_in[6];
  float* out = (float*)d_out;

  unsigned* gridA = (unsigned*)d_ws;          // 16.4 MB
  unsigned* gridB = gridA + kGridWords;       // 16.4 MB
  (void)ws_size;

  hipLaunchKernelGGL(repack_grids, dim3((kNB * 4 + 255) / 256), dim3(256), 0,
                     stream, density, off_c, emo_c, gridA, gridB);

  hipLaunchKernelGGL(dvgo_fwd, dim3(kR), dim3(256), 0, stream,
                     rays_o, rays_d, jitter, em, gridA, gridB, out);
}